// Round 4
// baseline (373.452 us; speedup 1.0000x reference)
//
#include <hip/hip_runtime.h>
#include <cstdint>

#define NROW 6144
#define KDIM 128
#define NLAB 200
#define C_COEF (-0.28719499063341177f)   /* -ln(99)/16 ; A_COEF = 2 exactly */
#define UBV 64.0f

typedef _Float16 f16x8 __attribute__((ext_vector_type(8)));
typedef float f32x4 __attribute__((ext_vector_type(4)));
typedef __attribute__((address_space(1))) const void as1c_void;
typedef __attribute__((address_space(3))) void as3_void;

__device__ __forceinline__ float softplus_f(float x){
  return fmaxf(x, 0.f) + __logf(1.f + __expf(-fabsf(x)));
}
__device__ __forceinline__ float waveRedF(float v){
#pragma unroll
  for (int o = 32; o; o >>= 1) v += __shfl_down(v, o, 64);
  return v;
}
__device__ __forceinline__ int waveRedI(int v){
#pragma unroll
  for (int o = 32; o; o >>= 1) v += __shfl_down(v, o, 64);
  return v;
}
__device__ __forceinline__ int bucket_of(float v){
  int b = (int)floorf(v * 2.f) + 128;
  return b < 0 ? 0 : (b > 255 ? 255 : b);
}
__device__ __forceinline__ unsigned key16_of(_Float16 h){
  unsigned short b = __builtin_bit_cast(unsigned short, h);
  return (b & 0x8000u) ? (unsigned)((unsigned short)~b) : (unsigned)(b | 0x8000u);
}
__device__ __forceinline__ float key16_dec(unsigned k){
  unsigned short b = (k & 0x8000u) ? (unsigned short)(k & 0x7FFFu)
                                   : (unsigned short)(~k & 0xFFFFu);
  return (float)__builtin_bit_cast(_Float16, b);
}

// ---------------- labels + per-label histogram ----------------
__global__ void k_label(const int* __restrict__ y, unsigned char* __restrict__ lab,
                        int* __restrict__ cnt){
  const int row = blockIdx.x;
  const int t = threadIdx.x;
  if (t < NLAB){
    if (y[(size_t)row * NLAB + t] != 0){
      lab[row] = (unsigned char)t;
      atomicAdd(&cnt[t], 1);
    }
  }
}

// ---------------- tanh -> swizzled f16, + quantization-loss partial ----------------
__global__ __launch_bounds__(256) void k_tanh(const float* __restrict__ u,
    _Float16* __restrict__ uhswz, float* __restrict__ accf){
  const int tid = threadIdx.x;
  const int gid = blockIdx.x * 256 + tid;
  const int row = gid >> 4;
  const int h = gid & 15;
  const int g = h ^ (row & 7);
  const float* sp = u + (size_t)row * KDIM + g * 8;
  float q = 0.f;
  f16x8 o;
#pragma unroll
  for (int t = 0; t < 8; t++){
    float x = sp[t];
    float e2 = __expf(2.f * x);
    float th = 1.f - 2.f * __builtin_amdgcn_rcpf(e2 + 1.f);  // tanh, ~1e-6 err
    float sg = (th > 0.f) ? 1.f : ((th < 0.f) ? -1.f : 0.f);
    float d = th - sg;
    q += d * d;
    o[t] = (_Float16)th;
  }
  *(f16x8*)(uhswz + (size_t)row * KDIM + h * 8) = o;
  q = waveRedF(q);
  __shared__ float qb[4];
  if ((tid & 63) == 0) qb[tid >> 6] = q;
  __syncthreads();
  if (tid == 0) atomicAdd(&accf[0], qb[0] + qb[1] + qb[2] + qb[3]);
}

// ---------------- inner = uh @ uh^T -> f16 out via LDS-transpose epilogue ----------------
__global__ __launch_bounds__(256) void k_mm(const _Float16* __restrict__ A,
    _Float16* __restrict__ out, int row0){
  __shared__ __align__(16) _Float16 SH[2 * 128 * KDIM];   // 64 KB: As|Bs, reused as Cs
  _Float16* As = SH;
  _Float16* Bs = SH + 128 * KDIM;
  const int tid = threadIdx.x;
  const int wav = tid >> 6, lane = tid & 63;
  const int bj = blockIdx.x, bi = blockIdx.y;

  const char* Ag = (const char*)(A + (size_t)(row0 + bi * 128) * KDIM);
  const char* Bg = (const char*)(A + (size_t)(bj * 128) * KDIM);
  char* Asb = (char*)As;
  char* Bsb = (char*)Bs;
#pragma unroll
  for (int t = 0; t < 8; t++){
    const int ub = wav * 8192 + t * 1024;
    __builtin_amdgcn_global_load_lds((as1c_void*)(Ag + ub + lane * 16),
                                     (as3_void*)(Asb + ub), 16, 0, 0);
    __builtin_amdgcn_global_load_lds((as1c_void*)(Bg + ub + lane * 16),
                                     (as3_void*)(Bsb + ub), 16, 0, 0);
  }
  __syncthreads();

  const int quad = lane >> 4, l16 = lane & 15;
  const int wm = (wav >> 1) * 64, wn = (wav & 1) * 64;
  f32x4 acc[4][4];
#pragma unroll
  for (int im = 0; im < 4; im++)
#pragma unroll
    for (int in = 0; in < 4; in++)
      acc[im][in] = (f32x4){0.f, 0.f, 0.f, 0.f};

#pragma unroll
  for (int kb = 0; kb < 4; kb++){
    f16x8 af[4], bf[4];
#pragma unroll
    for (int i = 0; i < 4; i++){
      const int m = wm + i * 16 + l16;
      const int gidx = kb * 4 + quad;
      af[i] = *(const f16x8*)(Asb + m * 256 + ((gidx ^ (m & 7)) << 4));
      const int n = wn + i * 16 + l16;
      bf[i] = *(const f16x8*)(Bsb + n * 256 + ((gidx ^ (n & 7)) << 4));
    }
#pragma unroll
    for (int im = 0; im < 4; im++)
#pragma unroll
      for (int in = 0; in < 4; in++)
        acc[im][in] = __builtin_amdgcn_mfma_f32_16x16x32_f16(af[im], bf[in], acc[im][in], 0, 0, 0);
  }
  __syncthreads();                                 // done reading As/Bs

  // scatter acc -> Cs (f16, stride 132 to break quad-row bank aliasing)
  _Float16* Cs = SH;                               // 128*132*2 = 33792 B
#pragma unroll
  for (int im = 0; im < 4; im++)
#pragma unroll
    for (int in = 0; in < 4; in++)
#pragma unroll
      for (int r = 0; r < 4; r++){
        const int rl = wm + im * 16 + quad * 4 + r;
        const int cl = wn + in * 16 + l16;
        Cs[rl * 132 + cl] = (_Float16)acc[im][in][r];
      }
  __syncthreads();

  // coalesced f16 write-out: 16 lanes cover one 256 B row segment
  _Float16* obase = out + (size_t)(bi * 128) * NROW + (size_t)bj * 128;
  const int s = tid & 15;
#pragma unroll
  for (int i = 0; i < 8; i++){
    const int r = (tid >> 4) + i * 16;
    f16x8 vv = *(const f16x8*)(Cs + r * 132 + s * 8);
    *(f16x8*)(obase + (size_t)r * NROW + s * 8) = vv;
  }
}

// ---------------- per-row stats + loss (register-resident row) ----------------
// Row lives in 12 VGPRs (f16x8 h[3]) + 24-bit sim mask. LDS ~5.5 KB.
// P0: load+classify+sums+count-histogram. P2: register rescan -> above-bucket
// sum + pivot-bucket compaction. Exact rank-count select with tie arithmetic.
// Fallback (cntB>512): binary search on f16 keyspace, register count scans.
__global__ __launch_bounds__(256) void k_stats(const _Float16* __restrict__ buf,
    const unsigned char* __restrict__ lab, const int* __restrict__ cnt,
    float* __restrict__ accf, int* __restrict__ acci, int row0){
  __shared__ int histc[256];                      // 1024 B
  __shared__ float simv[512];                     // 2048 B
  __shared__ float cand[512];                     // 2048 B
  __shared__ float rbuf[16];
  __shared__ int ctlI[8];   // 0:simCount 1:candCount 2:kr 3:cntB 4:pb 5:gtS 6:ltS 7:bsCnt
  __shared__ float ctlF[8]; // 2:piv 3:BP 4:BPd 5:piv2

  const int tid = threadIdx.x;
  const int lane = tid & 63;
  const int wav = tid >> 6;
  const int row = row0 + blockIdx.x;
  const int myl = lab[row];
  const int n_sim = cnt[myl];
  const int n_dis = NROW - n_sim;
  if (n_dis == 0 || n_sim == 0) return;           // uniform exit
  const int k1 = n_dis - (n_dis * 9) / 10;        // tail count (top-10% dissimilar)
  const int k2 = n_sim - (n_sim * 9) / 10;        // head count (bottom-10% similar)

  histc[tid] = 0;
  if (tid < 8){ ctlI[tid] = 0; ctlF[tid] = 0.f; }
  __syncthreads();                                // bar1

  // ---- P0: global -> registers, classify, sums, count histogram ----
  const f16x8* src = (const f16x8*)(buf + (size_t)blockIdx.x * NROW);
  const uint2* lsrc = (const uint2*)lab;
  f16x8 h[3];
  unsigned msim = 0;
  float sumS = 0.f, sumDS = 0.f;
#pragma unroll
  for (int it = 0; it < 3; ++it){
    const int g8 = it * 256 + tid;
    h[it] = src[g8];
    uint2 lw = lsrc[g8];
#pragma unroll
    for (int e = 0; e < 8; e++){
      unsigned lb = (e < 4) ? ((lw.x >> (e * 8)) & 255u) : ((lw.y >> ((e - 4) * 8)) & 255u);
      float hv = (float)h[it][e];
      if (lb == (unsigned)myl){
        msim |= 1u << (it * 8 + e);
        sumS += hv;
        int p = atomicAdd(&ctlI[0], 1);
        if (p < 512) simv[p] = hv;
      } else {
        sumDS += hv;
        atomicAdd(&histc[bucket_of(hv)], 1);
      }
    }
  }
  sumS = waveRedF(sumS); sumDS = waveRedF(sumDS);
  if (lane == 0){ rbuf[wav] = sumS; rbuf[4 + wav] = sumDS; }
  __syncthreads();                                // bar2
  sumS = rbuf[0] + rbuf[1] + rbuf[2] + rbuf[3];
  sumDS = rbuf[4] + rbuf[5] + rbuf[6] + rbuf[7];

  // ---- pivot bucket select (wave0, descending suffix count) ----
  if (wav == 0){
    int c[4]; int part = 0;
#pragma unroll
    for (int d = 0; d < 4; d++){ c[d] = histc[4 * lane + d]; part += c[d]; }
    int suf = part;
#pragma unroll
    for (int o = 1; o < 64; o <<= 1){
      int x = __shfl_down(suf, o, 64);
      if (lane + o < 64) suf += x;
    }
    int cum = suf - part;                         // count in buckets above group
#pragma unroll
    for (int d = 3; d >= 0; --d){
      if (k1 > cum && k1 <= cum + c[d]){
        ctlI[2] = k1 - cum;                       // rank within bucket (from top)
        ctlI[3] = c[d];                           // bucket population
        ctlI[4] = 4 * lane + d;                   // pivot bucket
      }
      cum += c[d];
    }
  }
  __syncthreads();                                // bar3
  const int pb = ctlI[4];
  const int cntB = ctlI[3];
  const int kr0 = ctlI[2];

  // ---- P2: register rescan -> above-bucket sum + pivot-bucket compaction ----
  float sAb = 0.f;
#pragma unroll
  for (int it = 0; it < 3; ++it){
#pragma unroll
    for (int e = 0; e < 8; e++){
      if ((msim >> (it * 8 + e)) & 1) continue;
      float hv = (float)h[it][e];
      int b = bucket_of(hv);
      if (b > pb) sAb += hv;
      else if (b == pb && cntB <= 512){
        int p = atomicAdd(&ctlI[1], 1);
        if (p < 512) cand[p] = hv;
      }
    }
  }
  sAb = waveRedF(sAb);
  if (lane == 0) rbuf[8 + wav] = sAb;
  __syncthreads();                                // bar4
  sAb = rbuf[8] + rbuf[9] + rbuf[10] + rbuf[11];

  float dSum;
  if (cntB <= 512){
    const int nc = ctlI[1];
    for (int t = tid; t < nc; t += 256){
      float vt = cand[t];
      int gt = 0, eq = 0;
      for (int j = 0; j < nc; j++){
        float vj = cand[j];
        gt += (vj > vt); eq += (vj == vt);
      }
      if (gt < kr0 && kr0 <= gt + eq){ ctlF[2] = vt; ctlI[5] = gt; }
    }
    __syncthreads();                              // bar5
    const float piv = ctlF[2];
    const int gtS = ctlI[5];
    float sg = 0.f;
    for (int t = tid; t < nc; t += 256){
      float v = cand[t];
      if (v > piv) sg += v;
    }
    sg = waveRedF(sg);
    if (lane == 0) rbuf[wav] = sg;
    __syncthreads();                              // bar6
    sg = rbuf[0] + rbuf[1] + rbuf[2] + rbuf[3];
    dSum = sAb + sg + (float)(kr0 - gtS) * piv;
  } else {
    // guard path: exact k-th largest f16 key in pivot bucket via binary search
    unsigned lo = 0u, hi = 65535u;
    while (lo < hi){
      unsigned mid = (lo + hi) >> 1;
      if (tid == 0) ctlI[7] = 0;
      __syncthreads();
      int c = 0;
#pragma unroll
      for (int it = 0; it < 3; ++it)
#pragma unroll
        for (int e = 0; e < 8; e++){
          if ((msim >> (it * 8 + e)) & 1) continue;
          float hv = (float)h[it][e];
          if (bucket_of(hv) == pb && key16_of(h[it][e]) > mid) c++;
        }
      c = waveRedI(c);
      if (lane == 0) atomicAdd(&ctlI[7], c);
      __syncthreads();
      int cgt = ctlI[7];
      if (cgt >= kr0) lo = mid + 1; else hi = mid;
      __syncthreads();
    }
    const unsigned kth = lo;
    float sg = 0.f; int cg = 0;
#pragma unroll
    for (int it = 0; it < 3; ++it)
#pragma unroll
      for (int e = 0; e < 8; e++){
        if ((msim >> (it * 8 + e)) & 1) continue;
        float hv = (float)h[it][e];
        if (bucket_of(hv) == pb && key16_of(h[it][e]) > kth){ sg += hv; cg++; }
      }
    sg = waveRedF(sg); cg = waveRedI(cg);
    if (lane == 0){ rbuf[wav] = sg; if (wav == 0) ctlI[7] = 0; }
    __syncthreads();
    if (lane == 0) atomicAdd(&ctlI[7], cg);
    __syncthreads();
    sg = rbuf[0] + rbuf[1] + rbuf[2] + rbuf[3];
    dSum = sAb + sg + (float)(kr0 - ctlI[7]) * key16_dec(kth);
  }
  __syncthreads();                                // converge

  // ---- sMin: k2-th smallest similar (exact rank-count on gathered list) ----
  int ns = ctlI[0]; if (ns > 512) ns = 512;
  for (int t = tid; t < ns; t += 256){
    float vt = simv[t];
    int lt = 0, eq = 0;
    for (int j = 0; j < ns; j++){
      float vj = simv[j];
      lt += (vj < vt); eq += (vj == vt);
    }
    if (lt < k2 && k2 <= lt + eq){ ctlF[5] = vt; ctlI[6] = lt; }
  }
  __syncthreads();
  const float piv2 = ctlF[5];
  const int ltS = ctlI[6];
  float slt = 0.f;
  for (int t = tid; t < ns; t += 256){
    float v = simv[t];
    if (v < piv2) slt += v;
  }
  slt = waveRedF(slt);
  if (lane == 0) rbuf[wav] = slt;
  __syncthreads();
  slt = rbuf[0] + rbuf[1] + rbuf[2] + rbuf[3];
  const float sSum = slt + (float)(k2 - ltS) * piv2;

  if (tid == 0){
    float meanS = fminf(fmaxf(sumS / fmaxf((float)n_sim, 1.f), 0.f), UBV);
    float meanDS = fminf(fmaxf(sumDS / fmaxf((float)n_dis, 1.f), 0.f), UBV);
    float dMax = fminf(fmaxf(dSum / fmaxf((float)k1, 1.f), 0.f), UBV);
    float sMin = fminf(fmaxf(sSum / fmaxf((float)k2, 1.f), 0.f), UBV);
    ctlF[3] = meanS - (UBV - meanS) / UBV * fabsf(meanS - dMax);   // BP
    ctlF[4] = meanDS + meanDS / UBV * fabsf(meanDS - sMin);        // BPd
  }
  __syncthreads();

  // ---- loss pass (registers) ----
  const float BP = ctlF[3], BPd = ctlF[4];
  float ap = 0.f, an = 0.f, cp = 0.f, cn = 0.f;
#pragma unroll
  for (int it = 0; it < 3; ++it){
#pragma unroll
    for (int e = 0; e < 8; e++){
      float v = (float)h[it][e];
      if ((msim >> (it * 8 + e)) & 1){
        if (v != BP){
          float dc = v - BP;
          float f = (v > BP) ? C_COEF * dc : (2.f * C_COEF) * dc;
          ap += softplus_f(f); cp += 1.f;
        }
      } else {
        if (v != BPd){
          float dcd = v - BPd;
          float f = (v < BPd) ? C_COEF * dcd : (2.f * C_COEF) * dcd;
          an += softplus_f(-f); cn += 1.f;
        }
      }
    }
  }
  ap = waveRedF(ap); an = waveRedF(an); cp = waveRedF(cp); cn = waveRedF(cn);
  if (lane == 0){ rbuf[wav] = ap; rbuf[4 + wav] = an; rbuf[8 + wav] = cp; rbuf[12 + wav] = cn; }
  __syncthreads();
  if (tid == 0){
    ap = rbuf[0] + rbuf[1] + rbuf[2] + rbuf[3];
    an = rbuf[4] + rbuf[5] + rbuf[6] + rbuf[7];
    cp = rbuf[8] + rbuf[9] + rbuf[10] + rbuf[11];
    cn = rbuf[12] + rbuf[13] + rbuf[14] + rbuf[15];
    atomicAdd(&accf[1], ap / fmaxf(cp, 1.f));
    atomicAdd(&accf[2], an / fmaxf(cn, 1.f));
    atomicAdd(&acci[3], 1);
  }
}

__global__ void k_final(const float* __restrict__ accf, const int* __restrict__ acci,
                        float* __restrict__ out){
  if (threadIdx.x == 0 && blockIdx.x == 0){
    int c = acci[3];
    float posL = 0.f, navL = 0.f;
    if (c > 0){ posL = accf[1] / (float)c; navL = accf[2] / (float)c; }
    out[0] = posL + navL + 0.1f * (accf[0] / (float)(NROW * KDIM));
  }
}

extern "C" void kernel_launch(void* const* d_in, const int* in_sizes, int n_in,
                              void* d_out, int out_size, void* d_ws, size_t ws_size,
                              hipStream_t stream){
  const float* u = (const float*)d_in[0];
  const int* y = (const int*)d_in[1];
  char* ws = (char*)d_ws;
  float* accf = (float*)ws;                       // [0]=qSum [1]=posSum [2]=negSum
  int* acci = (int*)ws;                           // [3]=validCount
  int* cnt = (int*)(ws + 64);                     // 256 ints
  unsigned char* lab = (unsigned char*)(ws + 4096);
  _Float16* uhswz = (_Float16*)(ws + 16384);
  const size_t ibufOff = 16384 + (size_t)NROW * KDIM * 2;   // 16B aligned
  _Float16* ibuf = (_Float16*)(ws + ibufOff);

  hipMemsetAsync(d_ws, 0, 4096, stream);
  k_label<<<NROW, 256, 0, stream>>>(y, lab, cnt);
  k_tanh<<<(NROW * 16) / 256, 256, 0, stream>>>(u, uhswz, accf);

  size_t avail = (ws_size > ibufOff) ? ws_size - ibufOff : 0;
  long maxRows = (long)(avail / ((size_t)NROW * 2));
  maxRows = (maxRows / 128) * 128;
  if (maxRows > NROW) maxRows = NROW;
  if (maxRows < 128) maxRows = 128;

  for (int r0 = 0; r0 < NROW; r0 += (int)maxRows){
    int rows = NROW - r0;
    if (rows > maxRows) rows = (int)maxRows;
    k_mm<<<dim3(48, rows / 128), 256, 0, stream>>>(uhswz, ibuf, r0);
    k_stats<<<rows, 256, 0, stream>>>(ibuf, lab, cnt, accf, acci, r0);
  }
  k_final<<<1, 64, 0, stream>>>(accf, acci, (float*)d_out);
}

// Round 5
// 365.135 us; speedup vs baseline: 1.0228x; 1.0228x over previous
//
#include <hip/hip_runtime.h>
#include <cstdint>

#define NROW 6144
#define KDIM 128
#define NLAB 200
#define C_COEF (-0.28719499063341177f)   /* -ln(99)/16 ; A_COEF = 2 exactly */
#define UBV 64.0f

typedef _Float16 f16x8 __attribute__((ext_vector_type(8)));
typedef float f32x4 __attribute__((ext_vector_type(4)));
typedef __attribute__((address_space(1))) const void as1c_void;
typedef __attribute__((address_space(3))) void as3_void;

__device__ __forceinline__ float softplus_f(float x){
  return fmaxf(x, 0.f) + __logf(1.f + __expf(-fabsf(x)));
}
__device__ __forceinline__ float waveRedF(float v){
#pragma unroll
  for (int o = 32; o; o >>= 1) v += __shfl_down(v, o, 64);
  return v;
}
__device__ __forceinline__ int waveRedI(int v){
#pragma unroll
  for (int o = 32; o; o >>= 1) v += __shfl_down(v, o, 64);
  return v;
}
__device__ __forceinline__ int bucket_of(float v){
  int b = (int)floorf(v * 2.f) + 128;
  return b < 0 ? 0 : (b > 255 ? 255 : b);
}

// ---------------- labels + per-label histogram + member lists ----------------
__global__ void k_label(const int* __restrict__ y, unsigned char* __restrict__ lab,
                        int* __restrict__ cnt, int* __restrict__ simIdx){
  const int row = blockIdx.x;
  const int t = threadIdx.x;
  if (t < NLAB){
    if (y[(size_t)row * NLAB + t] != 0){
      lab[row] = (unsigned char)t;
      int p = atomicAdd(&cnt[t], 1);
      if (p < 512) simIdx[t * 512 + p] = row;
    }
  }
}

// ---------------- per-class 6144-bit similarity masks ----------------
__global__ __launch_bounds__(192) void k_clsmask(const unsigned char* __restrict__ lab,
                                                 unsigned* __restrict__ cm){
  const int c = blockIdx.x;       // class
  const int w = threadIdx.x;      // word: rows [w*32, w*32+32)
  const uint4* p = (const uint4*)(lab + w * 32);
  uint4 a = p[0], b = p[1];
  unsigned words[8] = {a.x, a.y, a.z, a.w, b.x, b.y, b.z, b.w};
  unsigned bits = 0;
#pragma unroll
  for (int j = 0; j < 8; j++)
#pragma unroll
    for (int i = 0; i < 4; i++)
      if (((words[j] >> (8 * i)) & 255u) == (unsigned)c) bits |= 1u << (4 * j + i);
  cm[c * 192 + w] = bits;
}

// ---------------- tanh -> swizzled f16, + quantization-loss partial ----------------
__global__ __launch_bounds__(256) void k_tanh(const float* __restrict__ u,
    _Float16* __restrict__ uhswz, float* __restrict__ accf){
  const int tid = threadIdx.x;
  const int gid = blockIdx.x * 256 + tid;
  const int row = gid >> 4;
  const int h = gid & 15;
  const int g = h ^ (row & 7);
  const float* sp = u + (size_t)row * KDIM + g * 8;
  float q = 0.f;
  f16x8 o;
#pragma unroll
  for (int t = 0; t < 8; t++){
    float x = sp[t];
    float e2 = __expf(2.f * x);
    float th = 1.f - 2.f * __builtin_amdgcn_rcpf(e2 + 1.f);  // tanh, ~1e-6 err
    float sg = (th > 0.f) ? 1.f : ((th < 0.f) ? -1.f : 0.f);
    float d = th - sg;
    q += d * d;
    o[t] = (_Float16)th;
  }
  *(f16x8*)(uhswz + (size_t)row * KDIM + h * 8) = o;
  q = waveRedF(q);
  __shared__ float qb[4];
  if ((tid & 63) == 0) qb[tid >> 6] = q;
  __syncthreads();
  if (tid == 0) atomicAdd(&accf[0], qb[0] + qb[1] + qb[2] + qb[3]);
}

// ---------------- inner = uh @ uh^T -> f16 out via LDS-transpose epilogue ----------------
__global__ __launch_bounds__(256) void k_mm(const _Float16* __restrict__ A,
    _Float16* __restrict__ out, int row0){
  __shared__ __align__(16) _Float16 SH[2 * 128 * KDIM];   // 64 KB: As|Bs, reused as Cs
  _Float16* As = SH;
  _Float16* Bs = SH + 128 * KDIM;
  const int tid = threadIdx.x;
  const int wav = tid >> 6, lane = tid & 63;
  const int bj = blockIdx.x, bi = blockIdx.y;

  const char* Ag = (const char*)(A + (size_t)(row0 + bi * 128) * KDIM);
  const char* Bg = (const char*)(A + (size_t)(bj * 128) * KDIM);
  char* Asb = (char*)As;
  char* Bsb = (char*)Bs;
#pragma unroll
  for (int t = 0; t < 8; t++){
    const int ub = wav * 8192 + t * 1024;
    __builtin_amdgcn_global_load_lds((as1c_void*)(Ag + ub + lane * 16),
                                     (as3_void*)(Asb + ub), 16, 0, 0);
    __builtin_amdgcn_global_load_lds((as1c_void*)(Bg + ub + lane * 16),
                                     (as3_void*)(Bsb + ub), 16, 0, 0);
  }
  __syncthreads();

  const int quad = lane >> 4, l16 = lane & 15;
  const int wm = (wav >> 1) * 64, wn = (wav & 1) * 64;
  f32x4 acc[4][4];
#pragma unroll
  for (int im = 0; im < 4; im++)
#pragma unroll
    for (int in = 0; in < 4; in++)
      acc[im][in] = (f32x4){0.f, 0.f, 0.f, 0.f};

#pragma unroll
  for (int kb = 0; kb < 4; kb++){
    f16x8 af[4], bf[4];
#pragma unroll
    for (int i = 0; i < 4; i++){
      const int m = wm + i * 16 + l16;
      const int gidx = kb * 4 + quad;
      af[i] = *(const f16x8*)(Asb + m * 256 + ((gidx ^ (m & 7)) << 4));
      const int n = wn + i * 16 + l16;
      bf[i] = *(const f16x8*)(Bsb + n * 256 + ((gidx ^ (n & 7)) << 4));
    }
#pragma unroll
    for (int im = 0; im < 4; im++)
#pragma unroll
      for (int in = 0; in < 4; in++)
        acc[im][in] = __builtin_amdgcn_mfma_f32_16x16x32_f16(af[im], bf[in], acc[im][in], 0, 0, 0);
  }
  __syncthreads();                                 // done reading As/Bs

  _Float16* Cs = SH;                               // 128*132*2 = 33792 B
#pragma unroll
  for (int im = 0; im < 4; im++)
#pragma unroll
    for (int in = 0; in < 4; in++)
#pragma unroll
      for (int r = 0; r < 4; r++){
        const int rl = wm + im * 16 + quad * 4 + r;
        const int cl = wn + in * 16 + l16;
        Cs[rl * 132 + cl] = (_Float16)acc[im][in][r];
      }
  __syncthreads();

  _Float16* obase = out + (size_t)(bi * 128) * NROW + (size_t)bj * 128;
  const int s = tid & 15;
#pragma unroll
  for (int i = 0; i < 8; i++){
    const int r = (tid >> 4) + i * 16;
    f16x8 vv = *(const f16x8*)(Cs + r * 132 + s * 8);
    *(f16x8*)(obase + (size_t)r * NROW + s * 8) = vv;
  }
}

// ---------------- per-row stats + loss (branch-free scans via class masks) ----------------
// P0: unconditional histogram+sum over all 6144 elems (~8 inst/elem), then a
// ~31-iteration sim-correction loop (member list). Pivot select on corrected
// counts; threshold-based rescan; side-loop sim losses. Exact tie arithmetic.
__global__ __launch_bounds__(256) void k_stats(const _Float16* __restrict__ buf,
    const unsigned char* __restrict__ lab, const int* __restrict__ cnt,
    const int* __restrict__ simIdx, const unsigned* __restrict__ cm,
    float* __restrict__ accf, int* __restrict__ acci, int row0){
  __shared__ __align__(16) _Float16 rowh[NROW];   // 12288 B
  __shared__ unsigned maskw[192];                 // 768 B class bitmask
  __shared__ int histc[256];                      // 1024 B
  __shared__ float simv[512];                     // 2048 B
  __shared__ float cand[512];                     // 2048 B
  __shared__ float rbuf[16];
  __shared__ int ctlI[8];   // 1:candCount 2:kr 3:cntB 4:pb 5:gtS 6:ltS 7:bsCnt
  __shared__ float ctlF[8]; // 2:piv 3:BP 4:BPd 5:piv2

  const int tid = threadIdx.x;
  const int lane = tid & 63;
  const int wav = tid >> 6;
  const int row = row0 + blockIdx.x;
  const int myl = lab[row];
  const int n_sim = cnt[myl];
  const int n_dis = NROW - n_sim;
  if (n_dis == 0 || n_sim == 0) return;           // uniform exit
  const int k1 = n_dis - (n_dis * 9) / 10;        // tail count (top-10% dissimilar)
  const int k2 = n_sim - (n_sim * 9) / 10;        // head count (bottom-10% similar)
  const int ns = (n_sim < 512) ? n_sim : 512;

  histc[tid] = 0;
  if (tid < 192) maskw[tid] = cm[myl * 192 + tid];
  if (tid < 8){ ctlI[tid] = 0; ctlF[tid] = 0.f; }
  __syncthreads();                                // bar1

  // ---- P0: branch-free load + histogram + total sum ----
  const f16x8* src = (const f16x8*)(buf + (size_t)blockIdx.x * NROW);
  const unsigned char* mbytes = (const unsigned char*)maskw;
  float sumAll = 0.f;
  unsigned msim = 0;
#pragma unroll
  for (int it = 0; it < 3; ++it){
    const int g8 = it * 256 + tid;
    f16x8 h8 = src[g8];
    ((f16x8*)rowh)[g8] = h8;
    msim |= (unsigned)mbytes[g8] << (8 * it);
#pragma unroll
    for (int e = 0; e < 8; e++){
      float v = (float)h8[e];
      sumAll += v;
      atomicAdd(&histc[bucket_of(v)], 1);
    }
  }
  __syncthreads();                                // bar2 (rowh+hist ready)

  // ---- sim corrections: gather simv, subtract from histogram ----
  float vs = 0.f;
  if (tid < ns){
    int idx = simIdx[myl * 512 + tid];
    float v = (float)rowh[idx];
    simv[tid] = v;
    vs = v;
    atomicAdd(&histc[bucket_of(v)], -1);
  }
  float r1 = waveRedF(sumAll), r2 = waveRedF(vs);
  if (lane == 0){ rbuf[wav] = r1; rbuf[4 + wav] = r2; }
  __syncthreads();                                // bar3
  const float sumAllT = rbuf[0] + rbuf[1] + rbuf[2] + rbuf[3];
  const float sumS = rbuf[4] + rbuf[5] + rbuf[6] + rbuf[7];
  const float sumDS = sumAllT - sumS;

  // ---- pivot bucket select (wave0, descending suffix count) ----
  if (wav == 0){
    int c[4]; int part = 0;
#pragma unroll
    for (int d = 0; d < 4; d++){ c[d] = histc[4 * lane + d]; part += c[d]; }
    int suf = part;
#pragma unroll
    for (int o = 1; o < 64; o <<= 1){
      int x = __shfl_down(suf, o, 64);
      if (lane + o < 64) suf += x;
    }
    int cum = suf - part;                         // count in buckets above group
#pragma unroll
    for (int d = 3; d >= 0; --d){
      if (k1 > cum && k1 <= cum + c[d]){
        ctlI[2] = k1 - cum;                       // rank within bucket (from top)
        ctlI[3] = c[d];                           // bucket population
        ctlI[4] = 4 * lane + d;                   // pivot bucket
      }
      cum += c[d];
    }
  }
  __syncthreads();                                // bar4
  const int pb = ctlI[4];
  const int cntB = ctlI[3];
  const int kr0 = ctlI[2];
  const float thrLo = (pb == 0)   ? -1e30f : (float)(pb - 128) * 0.5f;
  const float thrHi = (pb == 255) ?  1e30f : (float)(pb - 127) * 0.5f;

  // ---- rescan: above-bucket sum + pivot-bucket compaction (threshold tests) ----
  float sAb = 0.f;
#pragma unroll
  for (int it = 0; it < 3; ++it){
    const int g8 = it * 256 + tid;
    f16x8 h8 = ((const f16x8*)rowh)[g8];
#pragma unroll
    for (int e = 0; e < 8; e++){
      bool dis = !((msim >> (it * 8 + e)) & 1);
      float v = (float)h8[e];
      if (dis && v >= thrHi) sAb += v;
      else if (dis && v >= thrLo && cntB <= 512){
        int p = atomicAdd(&ctlI[1], 1);
        if (p < 512) cand[p] = v;
      }
    }
  }
  sAb = waveRedF(sAb);
  if (lane == 0) rbuf[8 + wav] = sAb;
  __syncthreads();                                // bar5
  sAb = rbuf[8] + rbuf[9] + rbuf[10] + rbuf[11];

  float dSum;
  if (cntB <= 512){
    const int nc = ctlI[1] < 512 ? ctlI[1] : 512;
    for (int t = tid; t < nc; t += 256){
      float vt = cand[t];
      int gt = 0, eq = 0;
      for (int j = 0; j < nc; j++){
        float vj = cand[j];
        gt += (vj > vt); eq += (vj == vt);
      }
      if (gt < kr0 && kr0 <= gt + eq){ ctlF[2] = vt; ctlI[5] = gt; }
    }
    __syncthreads();                              // bar6
    const float piv = ctlF[2];
    const int gtS = ctlI[5];
    float sg = 0.f;
    for (int t = tid; t < nc; t += 256){
      float v = cand[t];
      if (v > piv) sg += v;
    }
    sg = waveRedF(sg);
    if (lane == 0) rbuf[wav] = sg;
    __syncthreads();                              // bar7
    sg = rbuf[0] + rbuf[1] + rbuf[2] + rbuf[3];
    dSum = sAb + sg + (float)(kr0 - gtS) * piv;
  } else {
    // guard path (not expected): exact within-bucket select via f32 bisection
    // on f16-representable values using count scans.
    float lo = thrLo, hi = thrHi;
    float piv = thrLo;
    for (int itr = 0; itr < 30; ++itr){
      float mid = 0.5f * (lo + hi);
      if (tid == 0) ctlI[7] = 0;
      __syncthreads();
      int c = 0;
#pragma unroll
      for (int it = 0; it < 3; ++it){
        const int g8 = it * 256 + tid;
        f16x8 h8 = ((const f16x8*)rowh)[g8];
#pragma unroll
        for (int e = 0; e < 8; e++){
          bool dis = !((msim >> (it * 8 + e)) & 1);
          float v = (float)h8[e];
          if (dis && v >= thrLo && v < thrHi && v > mid) c++;
        }
      }
      c = waveRedI(c);
      if (lane == 0) atomicAdd(&ctlI[7], c);
      __syncthreads();
      if (ctlI[7] >= kr0) lo = mid; else hi = mid;
      __syncthreads();
      piv = lo;
    }
    // snap to the smallest f16 value > lo is approximated by lo itself after
    // 30 bisections (interval << f16 ulp); count strictly-greater and sum.
    if (tid == 0) ctlI[7] = 0;
    __syncthreads();
    float sg = 0.f; int cg = 0;
#pragma unroll
    for (int it = 0; it < 3; ++it){
      const int g8 = it * 256 + tid;
      f16x8 h8 = ((const f16x8*)rowh)[g8];
#pragma unroll
      for (int e = 0; e < 8; e++){
        bool dis = !((msim >> (it * 8 + e)) & 1);
        float v = (float)h8[e];
        if (dis && v >= thrLo && v < thrHi && v > piv){ sg += v; cg++; }
      }
    }
    sg = waveRedF(sg); cg = waveRedI(cg);
    if (lane == 0){ rbuf[wav] = sg; }
    __syncthreads();
    if (lane == 0) atomicAdd(&ctlI[7], cg);
    __syncthreads();
    sg = rbuf[0] + rbuf[1] + rbuf[2] + rbuf[3];
    dSum = sAb + sg + (float)(kr0 - ctlI[7]) * piv;
  }
  __syncthreads();                                // converge

  // ---- sMin: k2-th smallest similar (exact rank-count on gathered list) ----
  for (int t = tid; t < ns; t += 256){
    float vt = simv[t];
    int lt = 0, eq = 0;
    for (int j = 0; j < ns; j++){
      float vj = simv[j];
      lt += (vj < vt); eq += (vj == vt);
    }
    if (lt < k2 && k2 <= lt + eq){ ctlF[5] = vt; ctlI[6] = lt; }
  }
  __syncthreads();                                // bar8
  const float piv2 = ctlF[5];
  const int ltS = ctlI[6];
  float slt = 0.f;
  if (tid < ns){
    float v = simv[tid];
    if (v < piv2) slt = v;
  }
  slt = waveRedF(slt);
  if (lane == 0) rbuf[wav] = slt;
  __syncthreads();                                // bar9
  slt = rbuf[0] + rbuf[1] + rbuf[2] + rbuf[3];
  const float sSum = slt + (float)(k2 - ltS) * piv2;

  if (tid == 0){
    float meanS = fminf(fmaxf(sumS / fmaxf((float)n_sim, 1.f), 0.f), UBV);
    float meanDS = fminf(fmaxf(sumDS / fmaxf((float)n_dis, 1.f), 0.f), UBV);
    float dMax = fminf(fmaxf(dSum / fmaxf((float)k1, 1.f), 0.f), UBV);
    float sMin = fminf(fmaxf(sSum / fmaxf((float)k2, 1.f), 0.f), UBV);
    ctlF[3] = meanS - (UBV - meanS) / UBV * fabsf(meanS - dMax);   // BP
    ctlF[4] = meanDS + meanDS / UBV * fabsf(meanDS - sMin);        // BPd
  }
  __syncthreads();                                // bar10

  // ---- loss pass: branch-free dissimilar sweep + sim side-loop ----
  const float BP = ctlF[3], BPd = ctlF[4];
  float an = 0.f, cn = 0.f;
#pragma unroll
  for (int it = 0; it < 3; ++it){
    const int g8 = it * 256 + tid;
    f16x8 h8 = ((const f16x8*)rowh)[g8];
#pragma unroll
    for (int e = 0; e < 8; e++){
      float v = (float)h8[e];
      float dcd = v - BPd;
      float f = (v < BPd) ? C_COEF * dcd : (2.f * C_COEF) * dcd;
      float sp = softplus_f(-f);
      bool use = !((msim >> (it * 8 + e)) & 1) && (v != BPd);
      an += use ? sp : 0.f;
      cn += use ? 1.f : 0.f;
    }
  }
  float ap = 0.f, cp = 0.f;
  if (tid < ns){
    float v = simv[tid];
    if (v != BP){
      float dc = v - BP;
      float f = (v > BP) ? C_COEF * dc : (2.f * C_COEF) * dc;
      ap = softplus_f(f); cp = 1.f;
    }
  }
  ap = waveRedF(ap); an = waveRedF(an); cp = waveRedF(cp); cn = waveRedF(cn);
  if (lane == 0){ rbuf[wav] = ap; rbuf[4 + wav] = an; rbuf[8 + wav] = cp; rbuf[12 + wav] = cn; }
  __syncthreads();                                // bar11
  if (tid == 0){
    ap = rbuf[0] + rbuf[1] + rbuf[2] + rbuf[3];
    an = rbuf[4] + rbuf[5] + rbuf[6] + rbuf[7];
    cp = rbuf[8] + rbuf[9] + rbuf[10] + rbuf[11];
    cn = rbuf[12] + rbuf[13] + rbuf[14] + rbuf[15];
    atomicAdd(&accf[1], ap / fmaxf(cp, 1.f));
    atomicAdd(&accf[2], an / fmaxf(cn, 1.f));
    atomicAdd(&acci[3], 1);
  }
}

__global__ void k_final(const float* __restrict__ accf, const int* __restrict__ acci,
                        float* __restrict__ out){
  if (threadIdx.x == 0 && blockIdx.x == 0){
    int c = acci[3];
    float posL = 0.f, navL = 0.f;
    if (c > 0){ posL = accf[1] / (float)c; navL = accf[2] / (float)c; }
    out[0] = posL + navL + 0.1f * (accf[0] / (float)(NROW * KDIM));
  }
}

extern "C" void kernel_launch(void* const* d_in, const int* in_sizes, int n_in,
                              void* d_out, int out_size, void* d_ws, size_t ws_size,
                              hipStream_t stream){
  const float* u = (const float*)d_in[0];
  const int* y = (const int*)d_in[1];
  char* ws = (char*)d_ws;
  float* accf = (float*)ws;                        // [0]=qSum [1]=posSum [2]=negSum
  int* acci = (int*)ws;                            // [3]=validCount
  int* cnt = (int*)(ws + 64);                      // 256 ints
  unsigned char* lab = (unsigned char*)(ws + 4096);        // 6144 B
  int* simIdx = (int*)(ws + 12288);                // 200*512 ints = 409600 B
  unsigned* cmask = (unsigned*)(ws + 425984);      // 200*192 u32 = 153600 B
  _Float16* uhswz = (_Float16*)(ws + 589824);      // 1572864 B
  const size_t ibufOff = 589824 + (size_t)NROW * KDIM * 2; // 2162688, 16B aligned
  _Float16* ibuf = (_Float16*)(ws + ibufOff);

  hipMemsetAsync(d_ws, 0, 4096, stream);           // accumulators + class counts
  k_label<<<NROW, 256, 0, stream>>>(y, lab, cnt, simIdx);
  k_clsmask<<<NLAB, 192, 0, stream>>>(lab, cmask);
  k_tanh<<<(NROW * 16) / 256, 256, 0, stream>>>(u, uhswz, accf);

  size_t avail = (ws_size > ibufOff) ? ws_size - ibufOff : 0;
  long maxRows = (long)(avail / ((size_t)NROW * 2));
  maxRows = (maxRows / 128) * 128;
  if (maxRows > NROW) maxRows = NROW;
  if (maxRows < 128) maxRows = 128;

  for (int r0 = 0; r0 < NROW; r0 += (int)maxRows){
    int rows = NROW - r0;
    if (rows > maxRows) rows = (int)maxRows;
    k_mm<<<dim3(48, rows / 128), 256, 0, stream>>>(uhswz, ibuf, r0);
    k_stats<<<rows, 256, 0, stream>>>(ibuf, lab, cnt, simIdx, cmask, accf, acci, r0);
  }
  k_final<<<1, 64, 0, stream>>>(accf, acci, (float*)d_out);
}